// Round 14
// baseline (190.765 us; speedup 1.0000x reference)
//
#include <hip/hip_runtime.h>
#include <hip/hip_bf16.h>
#include <math.h>

#define POST 128
#define NI 129            // T+1
#define NJK 4225          // 65*65
#define NTOT 16512        // 129*128
#define KBLKS 134         // af k-blocks of 32
#define MBLKS 32          // 512/16
#define KHALF 67          // split-K: k-steps of 32 per block
#define PANEL_CLAMP 2163184u  // 4225*512 - 16 : last safe 16B source in a W1 panel

typedef __attribute__((ext_vector_type(8))) short bf16x8;
typedef __attribute__((ext_vector_type(4))) float f32x4;
typedef __attribute__((ext_vector_type(4))) unsigned int u32x4;

__device__ __forceinline__ unsigned short f2bf(float f){
    unsigned u = __builtin_bit_cast(unsigned, f);
    unsigned r = (u + 0x7FFFu + ((u >> 16) & 1u)) >> 16;   // RNE
    return (unsigned short)r;
}
__device__ __forceinline__ unsigned pack2(float a, float b){
    return (unsigned)f2bf(a) | ((unsigned)f2bf(b) << 16);
}
__device__ __forceinline__ unsigned cvtpk(float lo, float hi){
    unsigned r;
    asm("v_cvt_pk_bf16_f32 %0, %1, %2" : "=v"(r) : "v"(lo), "v"(hi));
    return r;
}

__device__ __forceinline__ void gload16(const void* g, void* l){
    __builtin_amdgcn_global_load_lds(
        (const __attribute__((address_space(1))) unsigned int*)g,
        (__attribute__((address_space(3))) unsigned int*)l, 16, 0, 0);
}

// ---------------- K1: build VA (bf16) in MFMA A-fragment granule order --------
__global__ void build_af(const float* __restrict__ audio,
                         const float* __restrict__ video,
                         uint4* __restrict__ af)
{
    int gid = blockIdx.x * 256 + threadIdx.x;
    if (gid >= KBLKS * MBLKS * 64) return;
    int lane = gid & 63;
    int mblk = (gid >> 6) & 31;
    int kblk = gid >> 11;
    int m  = mblk * 16 + (lane & 15);
    int k0 = kblk * 32 + (lane >> 4) * 8;
    float vals[8];
#pragma unroll
    for (int j = 0; j < 8; ++j){
        int k = k0 + j;
        float p = 0.f;
        if (k < NJK){
            int jj = k / 65;
            int kk = k - jj * 65;
            float a = (kk == 0) ? 1.f : audio[m * 64 + kk - 1];
            float v = (jj == 0) ? 1.f : video[m * 64 + jj - 1];
            p = a * v;
        }
        vals[j] = p;
    }
    uint4 o;
    o.x = pack2(vals[0], vals[1]);
    o.y = pack2(vals[2], vals[3]);
    o.z = pack2(vals[4], vals[5]);
    o.w = pack2(vals[6], vals[7]);
    af[gid] = o;
}

// ---------------- K2: fused Z = VA @ bf16(W1'), 4 blocks/CU -------------------
// 128x128 tile, BK=32, split-K x2, grid 1032 = 4 mt x 129 nt x 2 kb.
// 4 waves (2x2 of 64x64). Per iter:
//   A(ks)->regs (pinned) | vmcnt(4) bar [raw=tile ks] | CONVERT raw->frag[p]
//   (R12-verified, 0-conflict) | lgkm0 bar | STAGE(ks+1)->raw async | MFMA.
// LDS 32KB: raw fp32 16K (single) + frag bf16 2x8K. A never touches LDS.
__global__ __launch_bounds__(256, 4) void fusion_gemm(
    const float* __restrict__ W1,
    const uint4* __restrict__ af,
    float* __restrict__ Z0,
    float* __restrict__ Z1)
{
    __shared__ __align__(16) char lds[32768];
    // [0,16K): raw fp32 B [32k][128n] | [16K,32K): frag bf16 dbuf (2x8K)

    // bijective XCD swizzle (nwg=1032 = 8*129): 8 sub-blocks of one nt per XCD
    int orig = blockIdx.x;
    int xcd  = orig & 7;
    int w    = xcd * 129 + (orig >> 3);
    int nt  = w >> 3;         // 0..128
    int sub = w & 7;
    int mt  = sub & 3;        // 0..3
    int kb  = sub >> 2;       // 0..1

    int t    = threadIdx.x;
    int lane = t & 63;
    int wv   = t >> 6;
    int wm   = wv >> 1, wn = wv & 1;

    f32x4 acc[4][4] = {};

    const char* wpanel = (const char*)(W1 + (size_t)nt * (NJK * 128));

    int n_c = t & 127;        // convert: this thread's n-column
    int kg  = t >> 7;         // 0/1 : k-half (16 rows)

    int ks0 = kb * KHALF;

#define STAGE(ks_)                                                              \
    do {                                                                        \
        _Pragma("unroll")                                                       \
        for (int i_ = 0; i_ < 4; ++i_){                                         \
            int c_ = wv * 4 + i_;                                               \
            unsigned bo_ = (unsigned)(ks_) * 16384u                             \
                         + (unsigned)c_ * 1024u + (unsigned)lane * 16u;         \
            if (bo_ > PANEL_CLAMP) bo_ = PANEL_CLAMP;  /* tail-safe */          \
            gload16(wpanel + bo_, lds + c_ * 1024);                             \
        }                                                                       \
    } while (0)

    // prologue: stage tile ks0
    STAGE(ks0);

    for (int it = 0; it < KHALF; ++it){
        int ks = ks0 + it;
        int p  = it & 1;

        // ---- A fragments for tile ks -> regs (issue early, pin)
        const uint4* abase = af + ((size_t)ks * 32 + mt * 8 + wm * 4) * 64 + lane;
        uint4 vA0 = abase[0];
        uint4 vA1 = abase[64];
        uint4 vA2 = abase[128];
        uint4 vA3 = abase[192];
        __builtin_amdgcn_sched_barrier(0);

        // ---- wait B-stage(ks) (4 older loads); A's 4 stay in flight
        asm volatile("s_waitcnt vmcnt(4)" ::: "memory");
        __builtin_amdgcn_sched_barrier(0);
        __builtin_amdgcn_s_barrier();              // raw = tile ks, visible

        // ---- CONVERT raw fp32 [32k][128n] -> frag[p] bf16 [n][32k] swizzled
        {
            char* fragp = lds + 16384 + p * 8192;
            float v[16];
#pragma unroll
            for (int j = 0; j < 16; ++j)
                v[j] = *(const float*)(lds + (kg * 16 + j) * 512 + n_c * 4);
            u32x4 u0, u1;
            u0.x = cvtpk(v[0],  v[1]);  u0.y = cvtpk(v[2],  v[3]);
            u0.z = cvtpk(v[4],  v[5]);  u0.w = cvtpk(v[6],  v[7]);
            u1.x = cvtpk(v[8],  v[9]);  u1.y = cvtpk(v[10], v[11]);
            u1.z = cvtpk(v[12], v[13]); u1.w = cvtpk(v[14], v[15]);
            int swz = ((n_c >> 1) & 3) << 4;
            *(u32x4*)(fragp + ((n_c * 64 + kg * 32     ) ^ swz)) = u0;
            *(u32x4*)(fragp + ((n_c * 64 + kg * 32 + 16) ^ swz)) = u1;
        }
        asm volatile("s_waitcnt lgkmcnt(0)" ::: "memory");
        __builtin_amdgcn_sched_barrier(0);
        __builtin_amdgcn_s_barrier();              // frag[p] ready; raw free

        // ---- stage next tile's B into raw (async; lands before next entry wait)
        if (it + 1 < KHALF)
            STAGE(ks + 1);
        __builtin_amdgcn_sched_barrier(0);

        // ---- MFMA: A regs (compiler waits vmcnt(4): B newer) + frag[p]
        {
            const char* fragp = lds + 16384 + p * 8192;
            bf16x8 b[4];
#pragma unroll
            for (int g = 0; g < 4; ++g){
                int n = wn * 64 + g * 16 + (lane & 15);
                int byte = (n * 64 + (lane >> 4) * 16) ^ (((n >> 1) & 3) << 4);
                b[g] = *(const bf16x8*)(fragp + byte);
            }
            bf16x8 a0 = __builtin_bit_cast(bf16x8, vA0);
            bf16x8 a1 = __builtin_bit_cast(bf16x8, vA1);
            bf16x8 a2 = __builtin_bit_cast(bf16x8, vA2);
            bf16x8 a3 = __builtin_bit_cast(bf16x8, vA3);
#pragma unroll
            for (int g = 0; g < 4; ++g){
                acc[0][g] = __builtin_amdgcn_mfma_f32_16x16x32_bf16(a0, b[g], acc[0][g], 0, 0, 0);
                acc[1][g] = __builtin_amdgcn_mfma_f32_16x16x32_bf16(a1, b[g], acc[1][g], 0, 0, 0);
                acc[2][g] = __builtin_amdgcn_mfma_f32_16x16x32_bf16(a2, b[g], acc[2][g], 0, 0, 0);
                acc[3][g] = __builtin_amdgcn_mfma_f32_16x16x32_bf16(a3, b[g], acc[3][g], 0, 0, 0);
            }
        }
    }

    // epilogue: D layout col=lane&15, row=(lane>>4)*4+reg
    float* Zp = kb ? Z1 : Z0;
    int row0 = mt * 128 + wm * 64 + (lane >> 4) * 4;
    int col0 = nt * 128 + wn * 64 + (lane & 15);
#pragma unroll
    for (int f = 0; f < 4; ++f)
#pragma unroll
        for (int g = 0; g < 4; ++g)
#pragma unroll
            for (int r = 0; r < 4; ++r)
                Zp[(size_t)(row0 + f * 16 + r) * NTOT + col0 + g * 16] = acc[f][g][r];
}

// ---------------- K3: y1 = relu(b1 + sum_i t1_i * (Z0+Z1)); y2; sigmoid head ---
__global__ void tail_mlp(const float* __restrict__ Z0,
                         const float* __restrict__ Z1,
                         const float* __restrict__ text,
                         const float* __restrict__ b1,
                         const float* __restrict__ W2,
                         const float* __restrict__ b2,
                         const float* __restrict__ W3,
                         const float* __restrict__ b3,
                         float* __restrict__ out)
{
    int b   = blockIdx.x;     // 512
    int tid = threadIdx.x;    // 128
    __shared__ float t1s[NI];
    __shared__ float y1s[POST];
    __shared__ float red[2];

    t1s[tid + 1] = text[b * 128 + tid];
    if (tid == 0) t1s[0] = 1.f;
    __syncthreads();

    const float* z0 = Z0 + (size_t)b * NTOT;
    const float* z1 = Z1 + (size_t)b * NTOT;
    float acc = 0.f;
    for (int i = 0; i < NI; ++i)
        acc = fmaf(t1s[i], z0[i * 128 + tid] + z1[i * 128 + tid], acc);
    acc += b1[tid];
    float y1 = fmaxf(acc, 0.f);
    y1s[tid] = y1;
    __syncthreads();

    float a2 = b2[tid];
    for (int q = 0; q < 128; ++q)
        a2 = fmaf(y1s[q], W2[q * 128 + tid], a2);
    float y2 = fmaxf(a2, 0.f);

    float part = y2 * W3[tid];
#pragma unroll
    for (int off = 32; off > 0; off >>= 1)
        part += __shfl_down(part, off);
    if ((tid & 63) == 0) red[tid >> 6] = part;
    __syncthreads();
    if (tid == 0){
        float z = red[0] + red[1] + b3[0];
        out[b] = 6.f / (1.f + expf(-z)) - 3.f;
    }
}

extern "C" void kernel_launch(void* const* d_in, const int* in_sizes, int n_in,
                              void* d_out, int out_size, void* d_ws, size_t ws_size,
                              hipStream_t stream)
{
    const float* audio = (const float*)d_in[0];
    const float* video = (const float*)d_in[1];
    const float* text  = (const float*)d_in[2];
    const float* W1    = (const float*)d_in[3];
    const float* b1    = (const float*)d_in[4];
    const float* W2    = (const float*)d_in[5];
    const float* b2    = (const float*)d_in[6];
    const float* W3    = (const float*)d_in[7];
    const float* b3    = (const float*)d_in[8];
    float* out = (float*)d_out;

    char* ws = (char*)d_ws;
    uint4* af = (uint4*)ws;                       // 4,390,912 B
    float* Z0 = (float*)(ws + (8u  << 20));       // 33,816,576 B
    float* Z1 = (float*)(ws + (48u << 20));       // 33,816,576 B

    int af_granules = KBLKS * MBLKS * 64;         // 274432 threads
    build_af<<<(af_granules + 255) / 256, 256, 0, stream>>>(audio, video, af);
    fusion_gemm<<<1032, 256, 0, stream>>>(W1, af, Z0, Z1);
    tail_mlp<<<512, 128, 0, stream>>>(Z0, Z1, text, b1, W2, b2, W3, b3, out);
}

// Round 15
// 182.348 us; speedup vs baseline: 1.0462x; 1.0462x over previous
//
#include <hip/hip_runtime.h>
#include <hip/hip_bf16.h>
#include <math.h>

#define POST 128
#define NI 129            // T+1
#define NJK 4225          // 65*65
#define NTOT 16512        // 129*128
#define KBLKS 134         // af k-blocks of 32
#define MBLKS 32          // 512/16
#define KHALF 67          // split-K: k-steps of 32 per block
#define PANEL_CLAMP 2163184u  // 4225*512 - 16 : last safe 16B source in a W1 panel

typedef __attribute__((ext_vector_type(8))) short bf16x8;
typedef __attribute__((ext_vector_type(4))) float f32x4;
typedef __attribute__((ext_vector_type(4))) unsigned int u32x4;

__device__ __forceinline__ unsigned short f2bf(float f){
    unsigned u = __builtin_bit_cast(unsigned, f);
    unsigned r = (u + 0x7FFFu + ((u >> 16) & 1u)) >> 16;   // RNE
    return (unsigned short)r;
}
__device__ __forceinline__ unsigned pack2(float a, float b){
    return (unsigned)f2bf(a) | ((unsigned)f2bf(b) << 16);
}
__device__ __forceinline__ unsigned cvtpk(float lo, float hi){
    unsigned r;
    asm("v_cvt_pk_bf16_f32 %0, %1, %2" : "=v"(r) : "v"(lo), "v"(hi));
    return r;
}

__device__ __forceinline__ void gload16(const void* g, void* l){
    __builtin_amdgcn_global_load_lds(
        (const __attribute__((address_space(1))) unsigned int*)g,
        (__attribute__((address_space(3))) unsigned int*)l, 16, 0, 0);
}

// ---------------- K1: build VA (bf16) in MFMA A-fragment granule order --------
__global__ void build_af(const float* __restrict__ audio,
                         const float* __restrict__ video,
                         uint4* __restrict__ af)
{
    int gid = blockIdx.x * 256 + threadIdx.x;
    if (gid >= KBLKS * MBLKS * 64) return;
    int lane = gid & 63;
    int mblk = (gid >> 6) & 31;
    int kblk = gid >> 11;
    int m  = mblk * 16 + (lane & 15);
    int k0 = kblk * 32 + (lane >> 4) * 8;
    float vals[8];
#pragma unroll
    for (int j = 0; j < 8; ++j){
        int k = k0 + j;
        float p = 0.f;
        if (k < NJK){
            int jj = k / 65;
            int kk = k - jj * 65;
            float a = (kk == 0) ? 1.f : audio[m * 64 + kk - 1];
            float v = (jj == 0) ? 1.f : video[m * 64 + jj - 1];
            p = a * v;
        }
        vals[j] = p;
    }
    uint4 o;
    o.x = pack2(vals[0], vals[1]);
    o.y = pack2(vals[2], vals[3]);
    o.z = pack2(vals[4], vals[5]);
    o.w = pack2(vals[6], vals[7]);
    af[gid] = o;
}

// ---------------- K2: fused Z = VA @ bf16(W1')  -------------------------------
// 128x128 tile, BK=32, split-K x2, grid 1032 = 4 mt x 129 nt x 2 kb, 4 waves.
// raw B fp32 DOUBLE-buffered via gload_lds (stage issues a full iter early,
// counted vmcnt(8)); A direct global->regs; convert raw->frag (single buf)
// between the two barriers; MFMA reads frag b128 + A regs.
// LDS 40KB: raw 2x16K @0 | frag bf16 8K @32K.  4 blocks/CU.
__global__ __launch_bounds__(256, 4) void fusion_gemm(
    const float* __restrict__ W1,
    const uint4* __restrict__ af,
    float* __restrict__ Z0,
    float* __restrict__ Z1)
{
    __shared__ __align__(16) char lds[40960];

    // bijective XCD swizzle (nwg=1032 = 8*129): 8 sub-blocks of one nt per XCD
    int orig = blockIdx.x;
    int xcd  = orig & 7;
    int w    = xcd * 129 + (orig >> 3);
    int nt  = w >> 3;         // 0..128
    int sub = w & 7;
    int mt  = sub & 3;        // 0..3
    int kb  = sub >> 2;       // 0..1

    int t    = threadIdx.x;
    int lane = t & 63;
    int wv   = t >> 6;
    int wm   = wv >> 1, wn = wv & 1;

    f32x4 acc[4][4] = {};

    const char* wpanel = (const char*)(W1 + (size_t)nt * (NJK * 128));

    int n_c = t & 127;        // convert: this thread's n-column
    int kg  = t >> 7;         // 0/1 : k-half (16 rows)

    int ks0 = kb * KHALF;

#define STAGE(ks_, pb_)                                                         \
    do {                                                                        \
        char* dst_ = lds + (pb_) * 16384;                                       \
        _Pragma("unroll")                                                       \
        for (int i_ = 0; i_ < 4; ++i_){                                         \
            int c_ = wv * 4 + i_;                                               \
            unsigned bo_ = (unsigned)(ks_) * 16384u                             \
                         + (unsigned)c_ * 1024u + (unsigned)lane * 16u;         \
            if (bo_ > PANEL_CLAMP) bo_ = PANEL_CLAMP;  /* tail-safe */          \
            gload16(wpanel + bo_, dst_ + c_ * 1024);                            \
        }                                                                       \
    } while (0)

    // prologue: stage tile ks0 into raw0
    STAGE(ks0, 0);

    for (int it = 0; it < KHALF; ++it){
        int ks = ks0 + it;
        int p  = it & 1;

        // ---- A fragments for tile ks -> regs (issue early, pin)
        const uint4* abase = af + ((size_t)ks * 32 + mt * 8 + wm * 4) * 64 + lane;
        uint4 vA0 = abase[0];
        uint4 vA1 = abase[64];
        uint4 vA2 = abase[128];
        uint4 vA3 = abase[192];
        __builtin_amdgcn_sched_barrier(0);

        // ---- stage NEXT tile into raw[p^1] (in flight across this whole iter)
        if (it + 1 < KHALF)
            STAGE(ks + 1, p ^ 1);
        __builtin_amdgcn_sched_barrier(0);

        // ---- wait raw[p] (= STAGE(ks), issued a full iteration ago)
        if (it + 1 < KHALF){
            asm volatile("s_waitcnt vmcnt(8)" ::: "memory");  // A(4)+nextStage(4) remain
        } else {
            asm volatile("s_waitcnt vmcnt(4)" ::: "memory");  // A(4) remains
        }
        __builtin_amdgcn_sched_barrier(0);
        __builtin_amdgcn_s_barrier();              // raw[p] visible; frag free (prev MFMA done)

        // ---- CONVERT raw[p] fp32 [32k][128n] -> frag bf16 [n][32k] swizzled
        {
            const char* rawp = lds + p * 16384;
            char* fragp      = lds + 32768;
            float v[16];
#pragma unroll
            for (int j = 0; j < 16; ++j)
                v[j] = *(const float*)(rawp + (kg * 16 + j) * 512 + n_c * 4);
            u32x4 u0, u1;
            u0.x = cvtpk(v[0],  v[1]);  u0.y = cvtpk(v[2],  v[3]);
            u0.z = cvtpk(v[4],  v[5]);  u0.w = cvtpk(v[6],  v[7]);
            u1.x = cvtpk(v[8],  v[9]);  u1.y = cvtpk(v[10], v[11]);
            u1.z = cvtpk(v[12], v[13]); u1.w = cvtpk(v[14], v[15]);
            int swz = ((n_c >> 1) & 3) << 4;
            *(u32x4*)(fragp + ((n_c * 64 + kg * 32     ) ^ swz)) = u0;
            *(u32x4*)(fragp + ((n_c * 64 + kg * 32 + 16) ^ swz)) = u1;
        }
        asm volatile("s_waitcnt lgkmcnt(0)" ::: "memory");
        __builtin_amdgcn_sched_barrier(0);
        __builtin_amdgcn_s_barrier();              // frag ready

        // ---- MFMA: A regs + frag b128 reads
        {
            const char* fragp = lds + 32768;
            bf16x8 b[4];
#pragma unroll
            for (int g = 0; g < 4; ++g){
                int n = wn * 64 + g * 16 + (lane & 15);
                int byte = (n * 64 + (lane >> 4) * 16) ^ (((n >> 1) & 3) << 4);
                b[g] = *(const bf16x8*)(fragp + byte);
            }
            bf16x8 a0 = __builtin_bit_cast(bf16x8, vA0);
            bf16x8 a1 = __builtin_bit_cast(bf16x8, vA1);
            bf16x8 a2 = __builtin_bit_cast(bf16x8, vA2);
            bf16x8 a3 = __builtin_bit_cast(bf16x8, vA3);
#pragma unroll
            for (int g = 0; g < 4; ++g){
                acc[0][g] = __builtin_amdgcn_mfma_f32_16x16x32_bf16(a0, b[g], acc[0][g], 0, 0, 0);
                acc[1][g] = __builtin_amdgcn_mfma_f32_16x16x32_bf16(a1, b[g], acc[1][g], 0, 0, 0);
                acc[2][g] = __builtin_amdgcn_mfma_f32_16x16x32_bf16(a2, b[g], acc[2][g], 0, 0, 0);
                acc[3][g] = __builtin_amdgcn_mfma_f32_16x16x32_bf16(a3, b[g], acc[3][g], 0, 0, 0);
            }
        }
    }

    // epilogue: D layout col=lane&15, row=(lane>>4)*4+reg
    float* Zp = kb ? Z1 : Z0;
    int row0 = mt * 128 + wm * 64 + (lane >> 4) * 4;
    int col0 = nt * 128 + wn * 64 + (lane & 15);
#pragma unroll
    for (int f = 0; f < 4; ++f)
#pragma unroll
        for (int g = 0; g < 4; ++g)
#pragma unroll
            for (int r = 0; r < 4; ++r)
                Zp[(size_t)(row0 + f * 16 + r) * NTOT + col0 + g * 16] = acc[f][g][r];
}

// ---------------- K3: y1 = relu(b1 + sum_i t1_i * (Z0+Z1)); y2; sigmoid head ---
__global__ void tail_mlp(const float* __restrict__ Z0,
                         const float* __restrict__ Z1,
                         const float* __restrict__ text,
                         const float* __restrict__ b1,
                         const float* __restrict__ W2,
                         const float* __restrict__ b2,
                         const float* __restrict__ W3,
                         const float* __restrict__ b3,
                         float* __restrict__ out)
{
    int b   = blockIdx.x;     // 512
    int tid = threadIdx.x;    // 128
    __shared__ float t1s[NI];
    __shared__ float y1s[POST];
    __shared__ float red[2];

    t1s[tid + 1] = text[b * 128 + tid];
    if (tid == 0) t1s[0] = 1.f;
    __syncthreads();

    const float* z0 = Z0 + (size_t)b * NTOT;
    const float* z1 = Z1 + (size_t)b * NTOT;
    float acc = 0.f;
    for (int i = 0; i < NI; ++i)
        acc = fmaf(t1s[i], z0[i * 128 + tid] + z1[i * 128 + tid], acc);
    acc += b1[tid];
    float y1 = fmaxf(acc, 0.f);
    y1s[tid] = y1;
    __syncthreads();

    float a2 = b2[tid];
    for (int q = 0; q < 128; ++q)
        a2 = fmaf(y1s[q], W2[q * 128 + tid], a2);
    float y2 = fmaxf(a2, 0.f);

    float part = y2 * W3[tid];
#pragma unroll
    for (int off = 32; off > 0; off >>= 1)
        part += __shfl_down(part, off);
    if ((tid & 63) == 0) red[tid >> 6] = part;
    __syncthreads();
    if (tid == 0){
        float z = red[0] + red[1] + b3[0];
        out[b] = 6.f / (1.f + expf(-z)) - 3.f;
    }
}

extern "C" void kernel_launch(void* const* d_in, const int* in_sizes, int n_in,
                              void* d_out, int out_size, void* d_ws, size_t ws_size,
                              hipStream_t stream)
{
    const float* audio = (const float*)d_in[0];
    const float* video = (const float*)d_in[1];
    const float* text  = (const float*)d_in[2];
    const float* W1    = (const float*)d_in[3];
    const float* b1    = (const float*)d_in[4];
    const float* W2    = (const float*)d_in[5];
    const float* b2    = (const float*)d_in[6];
    const float* W3    = (const float*)d_in[7];
    const float* b3    = (const float*)d_in[8];
    float* out = (float*)d_out;

    char* ws = (char*)d_ws;
    uint4* af = (uint4*)ws;                       // 4,390,912 B
    float* Z0 = (float*)(ws + (8u  << 20));       // 33,816,576 B
    float* Z1 = (float*)(ws + (48u << 20));       // 33,816,576 B

    int af_granules = KBLKS * MBLKS * 64;         // 274432 threads
    build_af<<<(af_granules + 255) / 256, 256, 0, stream>>>(audio, video, af);
    fusion_gemm<<<1032, 256, 0, stream>>>(W1, af, Z0, Z1);
    tail_mlp<<<512, 128, 0, stream>>>(Z0, Z1, text, b1, W2, b2, W3, b3, out);
}